// Round 11
// baseline (516.037 us; speedup 1.0000x reference)
//
#include <hip/hip_runtime.h>
#include <hip/hip_bf16.h>
#include <math.h>

#define NEG_SLOPE 0.2f

constexpr int N_NODES = 50000;
constexpr int F_IN    = 512;
constexpr int HID     = 128;
constexpr int H1      = 4;
constexpr int E_EDGES = 800000;
constexpr int E_TOT   = E_EDGES + N_NODES;  // 850000 (self loops appended)
constexpr int DEG_CAP = 64;                 // max in-degree (Poisson(16)+1; P(>=64)~1e-13)

typedef __attribute__((ext_vector_type(8))) short short8;     // 8 bf16 = 4 VGPRs (MFMA frag)
typedef __attribute__((ext_vector_type(4))) float floatx4;    // MFMA acc
typedef __attribute__((ext_vector_type(2))) float f32x2;      // packed fp32 (v_pk_fma_f32)
typedef __attribute__((ext_vector_type(4))) unsigned short ushort4v;
typedef __attribute__((ext_vector_type(8))) unsigned short ushort8v;  // 16B

// fp32 -> bf16 round-to-nearest-even (finite inputs)
__device__ __forceinline__ unsigned short f2bf(float f) {
  union { float f; unsigned int u; } v; v.f = f;
  unsigned int u = v.u + 0x7FFFu + ((v.u >> 16) & 1u);
  return (unsigned short)(u >> 16);
}
__device__ __forceinline__ float bf_lo(unsigned int u) {
  union { unsigned int u; float f; } v; v.u = u << 16; return v.f;
}
__device__ __forceinline__ float bf_hi(unsigned int u) {
  union { unsigned int u; float f; } v; v.u = u & 0xFFFF0000u; return v.f;
}

template <int CPT>
__device__ __forceinline__ void store_vec(unsigned short* p, const float* v) {
#pragma unroll
  for (int c = 0; c < CPT; c += 4) {
    ushort4v o;
#pragma unroll
    for (int j = 0; j < 4; ++j) o[j] = f2bf(v[c + j]);
    *(ushort4v*)(p + c) = o;
  }
}
template <int CPT>
__device__ __forceinline__ void store_vec(float* p, const float* v) {
#pragma unroll
  for (int c = 0; c < CPT; c += 4) *(float4*)(p + c) = *(const float4*)(v + c);
}

__device__ __forceinline__ void async_load16(const void* g, void* lds) {
  __builtin_amdgcn_global_load_lds(
      (const __attribute__((address_space(1))) unsigned int*)g,
      (__attribute__((address_space(3))) unsigned int*)lds, 16, 0, 0);
}

// ---------------- prep: zero bucket counters + transpose-cast both weights ----------------
__global__ void prep_kernel(const float* __restrict__ W1, const float* __restrict__ W2,
                            unsigned short* __restrict__ W1t, unsigned short* __restrict__ W2t,
                            int* __restrict__ cnt) {
  int i = blockIdx.x * 256 + threadIdx.x;
  if (i < N_NODES) cnt[i] = 0;
  int j = i - N_NODES;                     // W1 [512][512] -> W1t [n][k]
  if (j >= 0 && j < 512 * 512) {
    int n = j >> 9, k = j & 511;
    W1t[j] = f2bf(W1[k * 512 + n]);
  }
  int l = i - N_NODES - 512 * 512;         // W2 [512][128] -> W2t [n][k]
  if (l >= 0 && l < 128 * 512) {
    int n = l >> 9, k = l & 511;
    W2t[l] = f2bf(W2[k * 128 + n]);
  }
}

// ---------------- gemm1: 2 HEADS PER BLOCK (A staged once per head-pair) ----------------
// R7-frozen K-loop schedule (stage -> sync -> MFMA -> sync; 3 rewrites all regressed).
// Output tile 128 rows x 256 cols; wave (wm,wn): rows wm*64+, cols wn*128+ (wn = local
// head). acc[4][8] = 128 VGPR. A fabric traffic 401 -> 200 MB (was once per head).
// XOR swizzle retained (conflicts measured 0). Cs epilogue aliases staging LDS.
// FILL: blocks beyond gemmBlocks run the edge-bucket build concurrently.
template <bool FILL>
__global__ __launch_bounds__(256) void gemm1_2h_kernel(
    const float* __restrict__ A, const unsigned short* __restrict__ Bt,
    unsigned short* __restrict__ C, const float* __restrict__ a_srcp,
    const float* __restrict__ a_dstp,
    float* __restrict__ alpha_src, float* __restrict__ alpha_dst,
    int M, int nRowTiles,
    const int* __restrict__ ei, int* __restrict__ cnt, int* __restrict__ adj,
    int gemmBlocks) {
  constexpr int K = 512, N = 512;
  __shared__ __align__(16) unsigned char smem[128 * 260 * 2];  // 66560 B union
  unsigned short* As = (unsigned short*)smem;             // [128*32] 8 KB
  unsigned short* Bs = (unsigned short*)(smem + 8192);    // [256*32] 16 KB
  unsigned short* Cs = (unsigned short*)smem;             // [128*260] epilogue alias
  __shared__ float red_s[128][2];   // per (row, local head)
  __shared__ float red_d[128][2];

  if (FILL && blockIdx.x >= gemmBlocks) {
    int i = (blockIdx.x - gemmBlocks) * 256 + threadIdx.x;
    if (i < E_TOT) {
      int s, d;
      if (i < E_EDGES) { s = ei[i]; d = ei[E_EDGES + i]; }
      else             { s = i - E_EDGES; d = s; }
      int pos = atomicAdd(&cnt[d], 1);
      if (pos < DEG_CAP) adj[d * DEG_CAP + pos] = s;
    }
    return;
  }

  int grp = blockIdx.x / 16;           // 8 rowtiles x 2 head-pairs per XCD group
  int w8 = blockIdx.x % 16;
  int hp = w8 >> 3;                    // head pair 0 or 1
  int rowTile = grp * 8 + (w8 & 7);
  if (rowTile >= nRowTiles) return;    // whole block exits together (uniform)
  int row0 = rowTile * 128;
  int col0 = hp * 256;

  int tid = threadIdx.x;
  int lane = tid & 63, wave = tid >> 6;
  int wm = wave & 1, wn = wave >> 1;   // wn = local head (0/1)
  int l15 = lane & 15, quad = lane >> 4;

  floatx4 acc[4][8];                   // 128 VGPRs
#pragma unroll
  for (int i = 0; i < 4; ++i)
#pragma unroll
    for (int j = 0; j < 8; ++j) acc[i][j] = (floatx4){0.f, 0.f, 0.f, 0.f};

  int r_in = (lane >> 2);
  // pre-swizzled source column: qsrc = (L&3) ^ ((L>>3)&3)  [(L>>3)&3 == (row>>1)&3]
  int c8sw = (((lane & 3) ^ ((lane >> 3) & 3)) * 8);
  // fragment-read swizzle: (row>>1)&3 == (l15>>1)&3 (other row terms are mult of 4)
  int sqrd = (quad ^ ((l15 >> 1) & 3)) * 8;

  for (int k0 = 0; k0 < K; k0 += 32) {
#pragma unroll
    for (int p = 0; p < 4; ++p) {      // B tile: 256 cols = 16 segs, 4 per wave
      int seg = wave * 4 + p;
      int r = seg * 16 + r_in;
      int gc = col0 + r;
      async_load16(Bt + (size_t)gc * K + k0 + c8sw, &Bs[seg * 512]);
    }
#pragma unroll
    for (int p = 0; p < 4; ++p) {      // A tile: fused fp32->bf16 cvt (1024 slots)
      int lin = tid + p * 256;
      int r = lin >> 3;                // 0..127
      int q = lin & 7;
      int gr = row0 + r; if (gr >= M) gr = M - 1;
      float4 f = *(const float4*)(A + (size_t)gr * K + k0 + q * 4);
      ushort4v o;
      o[0] = f2bf(f.x); o[1] = f2bf(f.y); o[2] = f2bf(f.z); o[3] = f2bf(f.w);
      int sl = ((q >> 1) ^ ((lin >> 4) & 3));   // swizzled dest slot
      *(ushort4v*)&As[r * 32 + sl * 8 + (q & 1) * 4] = o;
    }
    __syncthreads();

    short8 a[4], b[8];
#pragma unroll
    for (int mi = 0; mi < 4; ++mi)
      a[mi] = *(const short8*)&As[(wm * 64 + mi * 16 + l15) * 32 + sqrd];
#pragma unroll
    for (int ni = 0; ni < 8; ++ni)
      b[ni] = *(const short8*)&Bs[(wn * 128 + ni * 16 + l15) * 32 + sqrd];
#pragma unroll
    for (int mi = 0; mi < 4; ++mi)
#pragma unroll
      for (int ni = 0; ni < 8; ++ni)
        acc[mi][ni] = __builtin_amdgcn_mfma_f32_16x16x32_bf16(a[mi], b[ni], acc[mi][ni], 0, 0, 0);
    __syncthreads();   // also separates As/Bs (dead) from Cs (epilogue alias)
  }

  float a_s[8], a_d[8];
#pragma unroll
  for (int ni = 0; ni < 8; ++ni) {
    int cih = ni * 16 + l15;           // col within this wave's head
    a_s[ni] = a_srcp[(hp * 2 + wn) * HID + cih];
    a_d[ni] = a_dstp[(hp * 2 + wn) * HID + cih];
  }

  // ---- epilogue: per-head alpha dots + stage C tile to LDS (bf16, stride 260) ----
#pragma unroll
  for (int mi = 0; mi < 4; ++mi) {
#pragma unroll
    for (int r = 0; r < 4; ++r) {
      int rloc = wm * 64 + mi * 16 + quad * 4 + r;
      float ps = 0.f, pd = 0.f;
#pragma unroll
      for (int ni = 0; ni < 8; ++ni) {
        float v = acc[mi][ni][r];
        ps += v * a_s[ni];
        pd += v * a_d[ni];
        Cs[rloc * 260 + wn * 128 + ni * 16 + l15] = f2bf(v);
      }
#pragma unroll
      for (int off = 1; off < 16; off <<= 1) {
        ps += __shfl_xor(ps, off);
        pd += __shfl_xor(pd, off);
      }
      // 8 ni cover this head's full 128 cols -> reduction complete per (row, head)
      if (l15 == 0) { red_s[rloc][wn] = ps; red_d[rloc][wn] = pd; }
    }
  }
  __syncthreads();

  // ---- vectorized C store: 2 threads per row, 128 cols (256 B) each ----
  {
    int row = tid >> 1;
    int cc  = (tid & 1) * 128;
    int grow = row0 + row;
    if (grow < M) {
      const unsigned short* src = &Cs[row * 260 + cc];
      unsigned short* dst = &C[(size_t)grow * N + col0 + cc];
#pragma unroll
      for (int c = 0; c < 128; c += 8)
        *(ushort8v*)(dst + c) = *(const ushort8v*)(src + c);
    }
  }
  // ---- alpha store: 256 thr = 128 rows x 2 heads ----
  {
    int rrow = tid & 127, h = tid >> 7;
    int grow = row0 + rrow;
    if (grow < M) {
      alpha_src[(size_t)grow * H1 + hp * 2 + h] = red_s[rrow][h];
      alpha_dst[(size_t)grow * H1 + hp * 2 + h] = red_d[rrow][h];
    }
  }
}

// ---------------- generic GEMM (used for gemm2, BM=64) — R10 frozen ----------------
template <bool CVT_A, bool FILL, int BM>
__global__ __launch_bounds__(256) void gemm_bf16_kernel(
    const void* __restrict__ Araw, const unsigned short* __restrict__ Bt,
    unsigned short* __restrict__ C, const float* __restrict__ a_srcp,
    const float* __restrict__ a_dstp,
    float* __restrict__ alpha_src, float* __restrict__ alpha_dst,
    int M, int N, int K, int Hn, int nRowTiles,
    const int* __restrict__ ei, int* __restrict__ cnt, int* __restrict__ adj,
    int gemmBlocks) {
  constexpr int NWAVES = BM / 32;
  constexpr int WMW    = BM / 64;
  constexpr int BPW    = 8 / NWAVES;
  __shared__ __align__(16) unsigned char smem[BM * 132 * 2];
  unsigned short* As = (unsigned short*)smem;
  unsigned short* Bs = (unsigned short*)(smem + BM * 64);
  unsigned short* Cs = (unsigned short*)smem;
  __shared__ float red_s[128][2];
  __shared__ float red_d[128][2];

  if (FILL && blockIdx.x >= gemmBlocks) {
    int i = (blockIdx.x - gemmBlocks) * 256 + threadIdx.x;
    if (i < E_TOT) {
      int s, d;
      if (i < E_EDGES) { s = ei[i]; d = ei[E_EDGES + i]; }
      else             { s = i - E_EDGES; d = s; }
      int pos = atomicAdd(&cnt[d], 1);
      if (pos < DEG_CAP) adj[d * DEG_CAP + pos] = s;
    }
    return;
  }

  int grp = blockIdx.x / (8 * Hn);
  int w8 = blockIdx.x % (8 * Hn);
  int head = w8 >> 3;
  int rowTile = grp * 8 + (w8 & 7);
  if (rowTile >= nRowTiles) return;
  int row0 = rowTile * BM;
  int col0 = head * 128;

  int tid = threadIdx.x;
  int lane = tid & 63, wave = tid >> 6;
  int wm = wave % WMW, wn = wave / WMW;
  int l15 = lane & 15, quad = lane >> 4;

  floatx4 acc[4][4];
#pragma unroll
  for (int i = 0; i < 4; ++i)
#pragma unroll
    for (int j = 0; j < 4; ++j) acc[i][j] = (floatx4){0.f, 0.f, 0.f, 0.f};

  int r_in = (lane >> 2);
  int c8sw = (((lane & 3) ^ ((lane >> 3) & 3)) * 8);
  int sqrd = (quad ^ ((l15 >> 1) & 3)) * 8;

  for (int k0 = 0; k0 < K; k0 += 32) {
#pragma unroll
    for (int p = 0; p < BPW; ++p) {
      int seg = wave * BPW + p;
      int r = seg * 16 + r_in;
      int gc = col0 + r;
      async_load16(Bt + (size_t)gc * K + k0 + c8sw, &Bs[seg * 512]);
    }
    {
      const unsigned short* Ab = (const unsigned short*)Araw;
#pragma unroll
      for (int p = 0; p < 2; ++p) {
        int seg = wave * 2 + p;
        int r = seg * 16 + r_in;
        int gr = row0 + r; if (gr >= M) gr = M - 1;
        async_load16(Ab + (size_t)gr * K + k0 + c8sw, &As[seg * 512]);
      }
    }
    __syncthreads();

    short8 a[4], b[4];
#pragma unroll
    for (int mi = 0; mi < 4; ++mi)
      a[mi] = *(const short8*)&As[(wm * 64 + mi * 16 + l15) * 32 + sqrd];
#pragma unroll
    for (int ni = 0; ni < 4; ++ni)
      b[ni] = *(const short8*)&Bs[(wn * 64 + ni * 16 + l15) * 32 + sqrd];
#pragma unroll
    for (int mi = 0; mi < 4; ++mi)
#pragma unroll
      for (int ni = 0; ni < 4; ++ni)
        acc[mi][ni] = __builtin_amdgcn_mfma_f32_16x16x32_bf16(a[mi], b[ni], acc[mi][ni], 0, 0, 0);
    __syncthreads();
  }

  float a_s[4], a_d[4];
#pragma unroll
  for (int ni = 0; ni < 4; ++ni) {
    int cih = wn * 64 + ni * 16 + l15;
    a_s[ni] = a_srcp[head * HID + cih];
    a_d[ni] = a_dstp[head * HID + cih];
  }

#pragma unroll
  for (int mi = 0; mi < 4; ++mi) {
#pragma unroll
    for (int r = 0; r < 4; ++r) {
      int rloc = wm * 64 + mi * 16 + quad * 4 + r;
      float ps = 0.f, pd = 0.f;
#pragma unroll
      for (int ni = 0; ni < 4; ++ni) {
        float v = acc[mi][ni][r];
        ps += v * a_s[ni];
        pd += v * a_d[ni];
        Cs[rloc * 132 + wn * 64 + ni * 16 + l15] = f2bf(v);
      }
#pragma unroll
      for (int off = 1; off < 16; off <<= 1) {
        ps += __shfl_xor(ps, off);
        pd += __shfl_xor(pd, off);
      }
      if (l15 == 0) { red_s[rloc][wn] = ps; red_d[rloc][wn] = pd; }
    }
  }
  __syncthreads();

  {
    int row = tid >> 1;
    int cc  = (tid & 1) * 64;
    int grow = row0 + row;
    if (grow < M) {
      const unsigned short* src = &Cs[row * 132 + cc];
      unsigned short* dst = &C[(size_t)grow * N + col0 + cc];
#pragma unroll
      for (int c = 0; c < 64; c += 8)
        *(ushort8v*)(dst + c) = *(const ushort8v*)(src + c);
    }
  }
  if (tid < BM) {
    int grow = row0 + tid;
    if (grow < M) {
      alpha_src[(size_t)grow * Hn + head] = red_s[tid][0] + red_s[tid][1];
      alpha_dst[(size_t)grow * Hn + head] = red_d[tid][0] + red_d[tid][1];
    }
  }
}

// ---------------- segment softmax + weighted aggregation: ONE WAVE PER NODE ----------------
// 64-thr blocks (high TLP) + 8-deep rotating gather pipeline whose prologue is issued
// BEFORE softmax so the softmax phase hides the first LLC round trip. Packed fp32 FMA.
// At a structure-independent LLC-fetch floor (~3.8 TB/s, verified at occ 79% and 32%).
template <int H, typename OT>
__global__ __launch_bounds__(64) void aggregate_kernel(
    const unsigned short* __restrict__ h, const float* __restrict__ asrc,
    const float* __restrict__ adst, const int* __restrict__ cnt,
    const int* __restrict__ adj, const float* __restrict__ bias,
    OT* __restrict__ out, int apply_elu) {
  constexpr int CPT = 8;
  constexpr int CH = H * HID;          // 512 (H=4) or 128 (H=1)
  constexpr int NCH = CH / CPT;        // lanes covering channels (64 or 16)
  constexpr int SLOTS = 64 / NCH;      // edge slots per wave (1 or 4)
  __shared__ float p_sh[64 * H];
  __shared__ int ro_sh[64];            // src byte offset into h

  const int node = blockIdx.x;
  const int lane = threadIdx.x;
  int deg = cnt[node];
  if (deg > DEG_CAP) deg = DEG_CAP;

  int s_i = 0;
  if (lane < deg) s_i = adj[node * DEG_CAP + lane];
  ro_sh[lane] = s_i * (CH * 2);
  float ar[H];
  if constexpr (H == 4) {
    float4 f = (lane < deg) ? *(const float4*)(asrc + (size_t)s_i * 4)
                            : make_float4(0.f, 0.f, 0.f, 0.f);
    ar[0] = f.x; ar[1] = f.y; ar[2] = f.z; ar[3] = f.w;
  } else {
    ar[0] = (lane < deg) ? asrc[s_i] : 0.f;
  }
  asm volatile("s_waitcnt lgkmcnt(0)" ::: "memory");  // ro_sh visible to own wave

  const int chlane = lane % NCH;
  const int slot = lane / NCH;
  const int ch = chlane * CPT;
  const int head = ch >> 7;            // /128
  const char* hb = (const char*)h + ch * 2;

  auto loadu = [&](uint4& U, int e) {
    if (e < deg) U = *(const uint4*)(hb + (unsigned)ro_sh[e]);
    else         U = make_uint4(0u, 0u, 0u, 0u);   // zero contribution, no traffic
  };

  // ---- prologue prefetch: 8 pipeline stages issued before softmax ----
  uint4 u0, u1, u2, u3, u4, u5, u6, u7;
  loadu(u0, slot);             loadu(u1, slot + SLOTS);
  loadu(u2, slot + 2 * SLOTS); loadu(u3, slot + 3 * SLOTS);
  loadu(u4, slot + 4 * SLOTS); loadu(u5, slot + 5 * SLOTS);
  loadu(u6, slot + 6 * SLOTS); loadu(u7, slot + 7 * SLOTS);

  // ---- logits + segment softmax (lane = edge), hides prefetch latency ----
#pragma unroll
  for (int hh = 0; hh < H; ++hh) {
    float v = ar[hh] + adst[node * H + hh];
    v = (v > 0.f) ? v : NEG_SLOPE * v;             // leaky_relu
    float lg = (lane < deg) ? v : -1e30f;
#pragma unroll
    for (int o = 32; o; o >>= 1) lg = fmaxf(lg, __shfl_xor(lg, o));
    float p = (lane < deg) ? __expf(v - lg) : 0.f;
    float s = p;
#pragma unroll
    for (int o = 32; o; o >>= 1) s += __shfl_xor(s, o);
    p_sh[lane * H + hh] = p * (1.f / (s + 1e-16f));
  }
  asm volatile("s_waitcnt lgkmcnt(0)" ::: "memory");  // p_sh visible to own wave

  f32x2 ac0 = {0.f, 0.f}, ac1 = {0.f, 0.f}, ac2v = {0.f, 0.f}, ac3 = {0.f, 0.f};
  auto consume = [&](const uint4& U, int e) {
    float w = p_sh[(e & 63) * H + head];           // finite even for padded edges (U==0)
    f32x2 wp = {w, w};
    f32x2 t;
    t.x = bf_lo(U.x); t.y = bf_hi(U.x); ac0  += t * wp;
    t.x = bf_lo(U.y); t.y = bf_hi(U.y); ac1  += t * wp;
    t.x = bf_lo(U.z); t.y = bf_hi(U.z); ac2v += t * wp;
    t.x = bf_lo(U.w); t.y = bf_hi(U.w); ac3  += t * wp;
  };

  // ---- rotating 8-deep pipeline: consume stage i, immediately reissue for e+8*SLOTS ----
  int base = 0;
  for (;;) {
    int nb = base + 8 * SLOTS;
    if (nb < deg) {                                // uniform per wave
      consume(u0, base + slot);             loadu(u0, nb + slot);
      consume(u1, base + slot + SLOTS);     loadu(u1, nb + slot + SLOTS);
      consume(u2, base + slot + 2 * SLOTS); loadu(u2, nb + slot + 2 * SLOTS);
      consume(u3, base + slot + 3 * SLOTS); loadu(u3, nb + slot + 3 * SLOTS);
      consume(u4, base + slot + 4 * SLOTS); loadu(u4, nb + slot + 4 * SLOTS);
      consume(u5, base + slot + 5 * SLOTS); loadu(u5, nb + slot + 5 * SLOTS);
      consume(u6, base + slot + 6 * SLOTS); loadu(u6, nb + slot + 6 * SLOTS);
      consume(u7, base + slot + 7 * SLOTS); loadu(u7, nb + slot + 7 * SLOTS);
      base = nb;
    } else {
      consume(u0, base + slot);             consume(u1, base + slot + SLOTS);
      consume(u2, base + slot + 2 * SLOTS); consume(u3, base + slot + 3 * SLOTS);
      consume(u4, base + slot + 4 * SLOTS); consume(u5, base + slot + 5 * SLOTS);
      consume(u6, base + slot + 6 * SLOTS); consume(u7, base + slot + 7 * SLOTS);
      break;
    }
  }

  // ---- cross-slot reduction (only for SLOTS>1, i.e. H=1) ----
#pragma unroll
  for (int o = NCH; o < 64; o <<= 1) {
    ac0.x  += __shfl_xor(ac0.x, o);  ac0.y  += __shfl_xor(ac0.y, o);
    ac1.x  += __shfl_xor(ac1.x, o);  ac1.y  += __shfl_xor(ac1.y, o);
    ac2v.x += __shfl_xor(ac2v.x, o); ac2v.y += __shfl_xor(ac2v.y, o);
    ac3.x  += __shfl_xor(ac3.x, o);  ac3.y  += __shfl_xor(ac3.y, o);
  }

  if (slot == 0) {
    float r[CPT] = {ac0.x, ac0.y, ac1.x, ac1.y, ac2v.x, ac2v.y, ac3.x, ac3.y};
#pragma unroll
    for (int c = 0; c < CPT; ++c) {
      float t = r[c] + bias[ch + c];
      if (apply_elu) t = (t > 0.f) ? t : (__expf(t) - 1.f);
      r[c] = t;
    }
    store_vec<CPT>(&out[(size_t)node * CH + ch], r);
  }
}

// ---------------- launch (5 dispatches total; fill folded into gemm1) ----------------
extern "C" void kernel_launch(void* const* d_in, const int* in_sizes, int n_in,
                              void* d_out, int out_size, void* d_ws, size_t ws_size,
                              hipStream_t stream) {
  const float* x      = (const float*)d_in[0];
  const int*   ei     = (const int*)d_in[1];
  const float* W1     = (const float*)d_in[2];
  const float* a_src1 = (const float*)d_in[3];
  const float* a_dst1 = (const float*)d_in[4];
  const float* b1     = (const float*)d_in[5];
  const float* W2     = (const float*)d_in[6];
  const float* a_src2 = (const float*)d_in[7];
  const float* a_dst2 = (const float*)d_in[8];
  const float* b2     = (const float*)d_in[9];
  float* out = (float*)d_out;

  float* ws   = (float*)d_ws;
  float* as1  = ws;                                  // N*4
  float* ad1  = as1 + N_NODES * H1;                  // N*4
  float* as2  = ad1 + N_NODES * H1;                  // N
  float* ad2  = as2 + N_NODES;                       // N
  unsigned short* bufA = (unsigned short*)(ad2 + N_NODES);        // N*512 bf16
  unsigned short* bufB = bufA + (size_t)N_NODES * 512;            // N*512 bf16
  unsigned short* hmidb = bufA;
  unsigned short* h1b   = bufB;
  unsigned short* h2b   = bufB;
  unsigned short* W1t   = bufB + (size_t)N_NODES * 512;           // 512*512 bf16
  unsigned short* W2t   = W1t + 512 * 512;                        // 128*512 bf16
  int* cnt = (int*)(W2t + 128 * 512);                // N
  int* adj = cnt + N_NODES;                          // N*64

  constexpr int NRT = (N_NODES + 127) / 128;         // 391 row tiles (gemm1)
  constexpr int NRT8 = ((NRT + 7) / 8) * 8;          // 392 padded
  constexpr int NRT2 = (N_NODES + 63) / 64;          // 782 row tiles (gemm2, BM=64)
  constexpr int NRT2_8 = ((NRT2 + 7) / 8) * 8;       // 784 padded
  constexpr int PREP_ITEMS = N_NODES + 512 * 512 + 128 * 512;
  constexpr int FILL_BLOCKS = (E_TOT + 255) / 256;   // 3321
  constexpr int GEMM1_BLOCKS = NRT8 * 2;             // 784 (2 head-pairs per rowtile)

  prep_kernel<<<(PREP_ITEMS + 255) / 256, 256, 0, stream>>>(W1, W2, W1t, W2t, cnt);

  // gemm1 (2-head blocks, fused A-cast) with fill blocks appended.
  gemm1_2h_kernel<true><<<GEMM1_BLOCKS + FILL_BLOCKS, 256, 0, stream>>>(
      x, W1t, h1b, a_src1, a_dst1, as1, ad1, N_NODES, NRT,
      ei, cnt, adj, GEMM1_BLOCKS);
  aggregate_kernel<4, unsigned short><<<N_NODES, 64, 0, stream>>>(
      h1b, as1, ad1, cnt, adj, b1, hmidb, 1);

  // gemm2: BM=64, 128-thread blocks (R10, neutral-verified).
  gemm_bf16_kernel<false, false, 64><<<NRT2_8, 128, 0, stream>>>(
      hmidb, W2t, h2b, a_src2, a_dst2, as2, ad2, N_NODES, 128, 512, 1, NRT2,
      nullptr, nullptr, nullptr, 0);
  aggregate_kernel<1, float><<<N_NODES, 64, 0, stream>>>(
      h2b, as2, ad2, cnt, adj, b2, out, 0);
}

// Round 12
// 462.208 us; speedup vs baseline: 1.1165x; 1.1165x over previous
//
#include <hip/hip_runtime.h>
#include <hip/hip_bf16.h>
#include <math.h>

#define NEG_SLOPE 0.2f

constexpr int N_NODES = 50000;
constexpr int F_IN    = 512;
constexpr int HID     = 128;
constexpr int H1      = 4;
constexpr int E_EDGES = 800000;
constexpr int E_TOT   = E_EDGES + N_NODES;  // 850000 (self loops appended)
constexpr int DEG_CAP = 64;                 // max in-degree (Poisson(16)+1; P(>=64)~1e-13)
constexpr int FILL_ITER = 4;                // grid-stride items per fill thread

typedef __attribute__((ext_vector_type(8))) short short8;     // 8 bf16 = 4 VGPRs (MFMA frag)
typedef __attribute__((ext_vector_type(4))) float floatx4;    // MFMA acc
typedef __attribute__((ext_vector_type(2))) float f32x2;      // packed fp32 (v_pk_fma_f32)
typedef __attribute__((ext_vector_type(4))) unsigned short ushort4v;
typedef __attribute__((ext_vector_type(8))) unsigned short ushort8v;  // 16B

// fp32 -> bf16 round-to-nearest-even (finite inputs)
__device__ __forceinline__ unsigned short f2bf(float f) {
  union { float f; unsigned int u; } v; v.f = f;
  unsigned int u = v.u + 0x7FFFu + ((v.u >> 16) & 1u);
  return (unsigned short)(u >> 16);
}
__device__ __forceinline__ float bf_lo(unsigned int u) {
  union { unsigned int u; float f; } v; v.u = u << 16; return v.f;
}
__device__ __forceinline__ float bf_hi(unsigned int u) {
  union { unsigned int u; float f; } v; v.u = u & 0xFFFF0000u; return v.f;
}

template <int CPT>
__device__ __forceinline__ void store_vec(unsigned short* p, const float* v) {
#pragma unroll
  for (int c = 0; c < CPT; c += 4) {
    ushort4v o;
#pragma unroll
    for (int j = 0; j < 4; ++j) o[j] = f2bf(v[c + j]);
    *(ushort4v*)(p + c) = o;
  }
}
template <int CPT>
__device__ __forceinline__ void store_vec(float* p, const float* v) {
#pragma unroll
  for (int c = 0; c < CPT; c += 4) *(float4*)(p + c) = *(const float4*)(v + c);
}

__device__ __forceinline__ void async_load16(const void* g, void* lds) {
  __builtin_amdgcn_global_load_lds(
      (const __attribute__((address_space(1))) unsigned int*)g,
      (__attribute__((address_space(3))) unsigned int*)lds, 16, 0, 0);
}

// ---------------- prep: zero bucket counters + transpose-cast both weights ----------------
__global__ void prep_kernel(const float* __restrict__ W1, const float* __restrict__ W2,
                            unsigned short* __restrict__ W1t, unsigned short* __restrict__ W2t,
                            int* __restrict__ cnt) {
  int i = blockIdx.x * 256 + threadIdx.x;
  if (i < N_NODES) cnt[i] = 0;
  int j = i - N_NODES;                     // W1 [512][512] -> W1t [n][k]
  if (j >= 0 && j < 512 * 512) {
    int n = j >> 9, k = j & 511;
    W1t[j] = f2bf(W1[k * 512 + n]);
  }
  int l = i - N_NODES - 512 * 512;         // W2 [512][128] -> W2t [n][k]
  if (l >= 0 && l < 128 * 512) {
    int n = l >> 9, k = l & 511;
    W2t[l] = f2bf(W2[k * 128 + n]);
  }
}

// ---------------- bf16 MFMA GEMM + fused alpha-dot epilogue ----------------
// FROZEN R7/R10 structure (best measured across 6 structural alternatives): single-buffer
// K-loop, stage -> sync -> MFMA -> sync, XOR swizzle (conflicts = 0), Cs epilogue tile
// aliasing the staging LDS, vectorized 16B C-store. template<BM>: 128 for gemm1, 64 for
// gemm2 (782 blocks fixes the 1.5-block/CU imbalance).
// FILL: blocks beyond gemmBlocks run the edge-bucket build, GRID-STRIDED 4 items/thread
// (3321 -> 831 blocks: same work, 4x less block setup/teardown in the tail).
template <bool CVT_A, bool FILL, int BM>
__global__ __launch_bounds__(256) void gemm_bf16_kernel(
    const void* __restrict__ Araw, const unsigned short* __restrict__ Bt,
    unsigned short* __restrict__ C, const float* __restrict__ a_srcp,
    const float* __restrict__ a_dstp,
    float* __restrict__ alpha_src, float* __restrict__ alpha_dst,
    int M, int N, int K, int Hn, int nRowTiles,
    const int* __restrict__ ei, int* __restrict__ cnt, int* __restrict__ adj,
    int gemmBlocks) {
  constexpr int NWAVES = BM / 32;          // 4 (BM=128) or 2 (BM=64); threads = BM*2
  constexpr int WMW    = BM / 64;          // wm-wave count: 2 or 1
  constexpr int BPW    = 8 / NWAVES;       // B-tile segs per wave: 2 or 4
  __shared__ __align__(16) unsigned char smem[BM * 132 * 2];  // union
  unsigned short* As = (unsigned short*)smem;             // [BM*32] K-loop
  unsigned short* Bs = (unsigned short*)(smem + BM * 64); // [128*32] K-loop
  unsigned short* Cs = (unsigned short*)smem;             // [BM*132] epilogue alias
  __shared__ float red_s[128][2];
  __shared__ float red_d[128][2];

  if (FILL && blockIdx.x >= gemmBlocks) {
    int base = (blockIdx.x - gemmBlocks) * (256 * FILL_ITER) + threadIdx.x;
#pragma unroll
    for (int it = 0; it < FILL_ITER; ++it) {
      int i = base + it * 256;
      if (i < E_TOT) {
        int s, d;
        if (i < E_EDGES) { s = ei[i]; d = ei[E_EDGES + i]; }
        else             { s = i - E_EDGES; d = s; }
        int pos = atomicAdd(&cnt[d], 1);
        if (pos < DEG_CAP) adj[d * DEG_CAP + pos] = s;
      }
    }
    return;
  }

  int grp = blockIdx.x / (8 * Hn);
  int w8 = blockIdx.x % (8 * Hn);
  int head = w8 >> 3;
  int rowTile = grp * 8 + (w8 & 7);
  if (rowTile >= nRowTiles) return;    // whole block exits together (uniform)
  int row0 = rowTile * BM;
  int col0 = head * 128;

  int tid = threadIdx.x;
  int lane = tid & 63, wave = tid >> 6;
  int wm = wave % WMW, wn = wave / WMW;
  int l15 = lane & 15, quad = lane >> 4;

  floatx4 acc[4][4];
#pragma unroll
  for (int i = 0; i < 4; ++i)
#pragma unroll
    for (int j = 0; j < 4; ++j) acc[i][j] = (floatx4){0.f, 0.f, 0.f, 0.f};

  int r_in = (lane >> 2);
  // pre-swizzled source column: qsrc = (L&3) ^ ((L>>3)&3)  [(L>>3)&3 == (row>>1)&3]
  int c8sw = (((lane & 3) ^ ((lane >> 3) & 3)) * 8);
  // fragment-read swizzle: (row>>1)&3 == (l15>>1)&3 (wm/mi terms are multiples of 4)
  int sqrd = (quad ^ ((l15 >> 1) & 3)) * 8;

  for (int k0 = 0; k0 < K; k0 += 32) {
#pragma unroll
    for (int p = 0; p < BPW; ++p) {        // B tile: 8 segs of 1KB over all waves
      int seg = wave * BPW + p;
      int r = seg * 16 + r_in;
      int gc = col0 + r;                   // N multiple of 128
      async_load16(Bt + (size_t)gc * K + k0 + c8sw, &Bs[seg * 512]);
    }
    if constexpr (CVT_A) {
      const float* Af = (const float*)Araw;  // BM=128 path only (256 threads)
#pragma unroll
      for (int p = 0; p < 4; ++p) {
        int lin = tid + p * 256;            // 0..1023
        int r = lin >> 3;                   // 0..127
        int q = lin & 7;                    // 0..7 (8B half-slot within row)
        int gr = row0 + r; if (gr >= M) gr = M - 1;
        float4 f = *(const float4*)(Af + (size_t)gr * K + k0 + q * 4);
        ushort4v o;
        o[0] = f2bf(f.x); o[1] = f2bf(f.y); o[2] = f2bf(f.z); o[3] = f2bf(f.w);
        int sl = ((q >> 1) ^ ((lin >> 4) & 3));   // swizzled dest slot
        *(ushort4v*)&As[r * 32 + sl * 8 + (q & 1) * 4] = o;
      }
    } else {
      const unsigned short* Ab = (const unsigned short*)Araw;
#pragma unroll
      for (int p = 0; p < 2; ++p) {        // A tile: BM/16 segs, 2 per wave
        int seg = wave * 2 + p;
        int r = seg * 16 + r_in;
        int gr = row0 + r; if (gr >= M) gr = M - 1;
        async_load16(Ab + (size_t)gr * K + k0 + c8sw, &As[seg * 512]);
      }
    }
    __syncthreads();

    short8 a[4], b[4];
#pragma unroll
    for (int mi = 0; mi < 4; ++mi)
      a[mi] = *(const short8*)&As[(wm * 64 + mi * 16 + l15) * 32 + sqrd];
#pragma unroll
    for (int ni = 0; ni < 4; ++ni)
      b[ni] = *(const short8*)&Bs[(wn * 64 + ni * 16 + l15) * 32 + sqrd];
#pragma unroll
    for (int mi = 0; mi < 4; ++mi)
#pragma unroll
      for (int ni = 0; ni < 4; ++ni)
        acc[mi][ni] = __builtin_amdgcn_mfma_f32_16x16x32_bf16(a[mi], b[ni], acc[mi][ni], 0, 0, 0);
    __syncthreads();   // also separates As/Bs (dead) from Cs (epilogue alias)
  }

  float a_s[4], a_d[4];
#pragma unroll
  for (int ni = 0; ni < 4; ++ni) {
    int cih = wn * 64 + ni * 16 + l15;
    a_s[ni] = a_srcp[head * HID + cih];
    a_d[ni] = a_dstp[head * HID + cih];
  }

  // ---- epilogue: alpha dots (reg) + stage C tile to LDS (bf16, padded stride 132) ----
#pragma unroll
  for (int mi = 0; mi < 4; ++mi) {
#pragma unroll
    for (int r = 0; r < 4; ++r) {
      int rloc = wm * 64 + mi * 16 + quad * 4 + r;
      float ps = 0.f, pd = 0.f;
#pragma unroll
      for (int ni = 0; ni < 4; ++ni) {
        float v = acc[mi][ni][r];
        ps += v * a_s[ni];
        pd += v * a_d[ni];
        Cs[rloc * 132 + wn * 64 + ni * 16 + l15] = f2bf(v);
      }
#pragma unroll
      for (int off = 1; off < 16; off <<= 1) {
        ps += __shfl_xor(ps, off);
        pd += __shfl_xor(pd, off);
      }
      if (l15 == 0) { red_s[rloc][wn] = ps; red_d[rloc][wn] = pd; }
    }
  }
  __syncthreads();

  // ---- vectorized C store: 2 threads per row, 64 cols (128 B) each ----
  {
    int row = tid >> 1;                    // BM*2 threads cover BM rows
    int cc  = (tid & 1) * 64;
    int grow = row0 + row;
    if (grow < M) {
      const unsigned short* src = &Cs[row * 132 + cc];
      unsigned short* dst = &C[(size_t)grow * N + col0 + cc];
#pragma unroll
      for (int c = 0; c < 64; c += 8)
        *(ushort8v*)(dst + c) = *(const ushort8v*)(src + c);
    }
  }
  if (tid < BM) {
    int grow = row0 + tid;
    if (grow < M) {
      alpha_src[(size_t)grow * Hn + head] = red_s[tid][0] + red_s[tid][1];
      alpha_dst[(size_t)grow * Hn + head] = red_d[tid][0] + red_d[tid][1];
    }
  }
}

// ---------------- segment softmax + weighted aggregation: ONE WAVE PER NODE ----------------
// 64-thr blocks (high TLP) + 8-deep rotating gather pipeline whose prologue is issued
// BEFORE softmax so the softmax phase hides the first LLC round trip. Packed fp32 FMA.
// At a structure-independent LLC-fetch floor (~3.8 TB/s, verified at occ 79% and 32%).
template <int H, typename OT>
__global__ __launch_bounds__(64) void aggregate_kernel(
    const unsigned short* __restrict__ h, const float* __restrict__ asrc,
    const float* __restrict__ adst, const int* __restrict__ cnt,
    const int* __restrict__ adj, const float* __restrict__ bias,
    OT* __restrict__ out, int apply_elu) {
  constexpr int CPT = 8;
  constexpr int CH = H * HID;          // 512 (H=4) or 128 (H=1)
  constexpr int NCH = CH / CPT;        // lanes covering channels (64 or 16)
  constexpr int SLOTS = 64 / NCH;      // edge slots per wave (1 or 4)
  __shared__ float p_sh[64 * H];
  __shared__ int ro_sh[64];            // src byte offset into h

  const int node = blockIdx.x;
  const int lane = threadIdx.x;
  int deg = cnt[node];
  if (deg > DEG_CAP) deg = DEG_CAP;

  int s_i = 0;
  if (lane < deg) s_i = adj[node * DEG_CAP + lane];
  ro_sh[lane] = s_i * (CH * 2);
  float ar[H];
  if constexpr (H == 4) {
    float4 f = (lane < deg) ? *(const float4*)(asrc + (size_t)s_i * 4)
                            : make_float4(0.f, 0.f, 0.f, 0.f);
    ar[0] = f.x; ar[1] = f.y; ar[2] = f.z; ar[3] = f.w;
  } else {
    ar[0] = (lane < deg) ? asrc[s_i] : 0.f;
  }
  asm volatile("s_waitcnt lgkmcnt(0)" ::: "memory");  // ro_sh visible to own wave

  const int chlane = lane % NCH;
  const int slot = lane / NCH;
  const int ch = chlane * CPT;
  const int head = ch >> 7;            // /128
  const char* hb = (const char*)h + ch * 2;

  auto loadu = [&](uint4& U, int e) {
    if (e < deg) U = *(const uint4*)(hb + (unsigned)ro_sh[e]);
    else         U = make_uint4(0u, 0u, 0u, 0u);   // zero contribution, no traffic
  };

  // ---- prologue prefetch: 8 pipeline stages issued before softmax ----
  uint4 u0, u1, u2, u3, u4, u5, u6, u7;
  loadu(u0, slot);             loadu(u1, slot + SLOTS);
  loadu(u2, slot + 2 * SLOTS); loadu(u3, slot + 3 * SLOTS);
  loadu(u4, slot + 4 * SLOTS); loadu(u5, slot + 5 * SLOTS);
  loadu(u6, slot + 6 * SLOTS); loadu(u7, slot + 7 * SLOTS);

  // ---- logits + segment softmax (lane = edge), hides prefetch latency ----
#pragma unroll
  for (int hh = 0; hh < H; ++hh) {
    float v = ar[hh] + adst[node * H + hh];
    v = (v > 0.f) ? v : NEG_SLOPE * v;             // leaky_relu
    float lg = (lane < deg) ? v : -1e30f;
#pragma unroll
    for (int o = 32; o; o >>= 1) lg = fmaxf(lg, __shfl_xor(lg, o));
    float p = (lane < deg) ? __expf(v - lg) : 0.f;
    float s = p;
#pragma unroll
    for (int o = 32; o; o >>= 1) s += __shfl_xor(s, o);
    p_sh[lane * H + hh] = p * (1.f / (s + 1e-16f));
  }
  asm volatile("s_waitcnt lgkmcnt(0)" ::: "memory");  // p_sh visible to own wave

  f32x2 ac0 = {0.f, 0.f}, ac1 = {0.f, 0.f}, ac2v = {0.f, 0.f}, ac3 = {0.f, 0.f};
  auto consume = [&](const uint4& U, int e) {
    float w = p_sh[(e & 63) * H + head];           // finite even for padded edges (U==0)
    f32x2 wp = {w, w};
    f32x2 t;
    t.x = bf_lo(U.x); t.y = bf_hi(U.x); ac0  += t * wp;
    t.x = bf_lo(U.y); t.y = bf_hi(U.y); ac1  += t * wp;
    t.x = bf_lo(U.z); t.y = bf_hi(U.z); ac2v += t * wp;
    t.x = bf_lo(U.w); t.y = bf_hi(U.w); ac3  += t * wp;
  };

  // ---- rotating 8-deep pipeline: consume stage i, immediately reissue for e+8*SLOTS ----
  int base = 0;
  for (;;) {
    int nb = base + 8 * SLOTS;
    if (nb < deg) {                                // uniform per wave
      consume(u0, base + slot);             loadu(u0, nb + slot);
      consume(u1, base + slot + SLOTS);     loadu(u1, nb + slot + SLOTS);
      consume(u2, base + slot + 2 * SLOTS); loadu(u2, nb + slot + 2 * SLOTS);
      consume(u3, base + slot + 3 * SLOTS); loadu(u3, nb + slot + 3 * SLOTS);
      consume(u4, base + slot + 4 * SLOTS); loadu(u4, nb + slot + 4 * SLOTS);
      consume(u5, base + slot + 5 * SLOTS); loadu(u5, nb + slot + 5 * SLOTS);
      consume(u6, base + slot + 6 * SLOTS); loadu(u6, nb + slot + 6 * SLOTS);
      consume(u7, base + slot + 7 * SLOTS); loadu(u7, nb + slot + 7 * SLOTS);
      base = nb;
    } else {
      consume(u0, base + slot);             consume(u1, base + slot + SLOTS);
      consume(u2, base + slot + 2 * SLOTS); consume(u3, base + slot + 3 * SLOTS);
      consume(u4, base + slot + 4 * SLOTS); consume(u5, base + slot + 5 * SLOTS);
      consume(u6, base + slot + 6 * SLOTS); consume(u7, base + slot + 7 * SLOTS);
      break;
    }
  }

  // ---- cross-slot reduction (only for SLOTS>1, i.e. H=1) ----
#pragma unroll
  for (int o = NCH; o < 64; o <<= 1) {
    ac0.x  += __shfl_xor(ac0.x, o);  ac0.y  += __shfl_xor(ac0.y, o);
    ac1.x  += __shfl_xor(ac1.x, o);  ac1.y  += __shfl_xor(ac1.y, o);
    ac2v.x += __shfl_xor(ac2v.x, o); ac2v.y += __shfl_xor(ac2v.y, o);
    ac3.x  += __shfl_xor(ac3.x, o);  ac3.y  += __shfl_xor(ac3.y, o);
  }

  if (slot == 0) {
    float r[CPT] = {ac0.x, ac0.y, ac1.x, ac1.y, ac2v.x, ac2v.y, ac3.x, ac3.y};
#pragma unroll
    for (int c = 0; c < CPT; ++c) {
      float t = r[c] + bias[ch + c];
      if (apply_elu) t = (t > 0.f) ? t : (__expf(t) - 1.f);
      r[c] = t;
    }
    store_vec<CPT>(&out[(size_t)node * CH + ch], r);
  }
}

// ---------------- launch (5 dispatches total; fill folded into gemm1) ----------------
extern "C" void kernel_launch(void* const* d_in, const int* in_sizes, int n_in,
                              void* d_out, int out_size, void* d_ws, size_t ws_size,
                              hipStream_t stream) {
  const float* x      = (const float*)d_in[0];
  const int*   ei     = (const int*)d_in[1];
  const float* W1     = (const float*)d_in[2];
  const float* a_src1 = (const float*)d_in[3];
  const float* a_dst1 = (const float*)d_in[4];
  const float* b1     = (const float*)d_in[5];
  const float* W2     = (const float*)d_in[6];
  const float* a_src2 = (const float*)d_in[7];
  const float* a_dst2 = (const float*)d_in[8];
  const float* b2     = (const float*)d_in[9];
  float* out = (float*)d_out;

  float* ws   = (float*)d_ws;
  float* as1  = ws;                                  // N*4
  float* ad1  = as1 + N_NODES * H1;                  // N*4
  float* as2  = ad1 + N_NODES * H1;                  // N
  float* ad2  = as2 + N_NODES;                       // N
  unsigned short* bufA = (unsigned short*)(ad2 + N_NODES);        // N*512 bf16
  unsigned short* bufB = bufA + (size_t)N_NODES * 512;            // N*512 bf16
  unsigned short* hmidb = bufA;
  unsigned short* h1b   = bufB;
  unsigned short* h2b   = bufB;
  unsigned short* W1t   = bufB + (size_t)N_NODES * 512;           // 512*512 bf16
  unsigned short* W2t   = W1t + 512 * 512;                        // 128*512 bf16
  int* cnt = (int*)(W2t + 128 * 512);                // N
  int* adj = cnt + N_NODES;                          // N*64

  constexpr int NRT = (N_NODES + 127) / 128;         // 391 row tiles (gemm1, BM=128)
  constexpr int NRT8 = ((NRT + 7) / 8) * 8;          // 392 padded
  constexpr int NRT2 = (N_NODES + 63) / 64;          // 782 row tiles (gemm2, BM=64)
  constexpr int NRT2_8 = ((NRT2 + 7) / 8) * 8;       // 784 padded
  constexpr int PREP_ITEMS = N_NODES + 512 * 512 + 128 * 512;
  constexpr int FILL_BLOCKS = (E_TOT + 256 * FILL_ITER - 1) / (256 * FILL_ITER);  // 831
  constexpr int GEMM1_BLOCKS = NRT8 * H1;            // 1568

  prep_kernel<<<(PREP_ITEMS + 255) / 256, 256, 0, stream>>>(W1, W2, W1t, W2t, cnt);

  // gemm1 (fused A-cast, BM=128) with grid-strided fill blocks appended.
  gemm_bf16_kernel<true, true, 128>
      <<<GEMM1_BLOCKS + FILL_BLOCKS, 256, 0, stream>>>(
      x, W1t, h1b, a_src1, a_dst1, as1, ad1, N_NODES, 512, 512, H1, NRT,
      ei, cnt, adj, GEMM1_BLOCKS);
  aggregate_kernel<4, unsigned short><<<N_NODES, 64, 0, stream>>>(
      h1b, as1, ad1, cnt, adj, b1, hmidb, 1);

  // gemm2: BM=64, 128-thread blocks (R10, neutral-verified; better balanced).
  gemm_bf16_kernel<false, false, 64><<<NRT2_8, 128, 0, stream>>>(
      hmidb, W2t, h2b, a_src2, a_dst2, as2, ad2, N_NODES, 128, 512, 1, NRT2,
      nullptr, nullptr, nullptr, 0);
  aggregate_kernel<1, float><<<N_NODES, 64, 0, stream>>>(
      h2b, as2, ad2, cnt, adj, b2, out, 0);
}